// Round 3
// baseline (3178.171 us; speedup 1.0000x reference)
//
#include <hip/hip_runtime.h>
#include <math.h>

#define D      1024
#define NHEADS 16
#define HDIM   64
#define NL     2
#define FF     4096
#define NGRP   15
#define VOC    2048
#define TOPK   50
#define MAXS   16
#define NB     256

struct Params {
    const float* talker; const float* code0; const float* temp; const float* unis;
    const float* heads;  const float* embeds;
    const float* ln1; const float* ln2; const float* lnf;
    const float* wq; const float* wk; const float* wv; const float* wo;
    const float* w1; const float* w2;
    float* out; float* ws;
};

// Coherence-point scalar access for cross-block mutable buffers (bypasses the
// non-coherent per-XCD caches; no cache-maintenance fences needed anywhere).
__device__ __forceinline__ float cload(const float* p) {
    return __hip_atomic_load(p, __ATOMIC_RELAXED, __HIP_MEMORY_SCOPE_AGENT);
}
__device__ __forceinline__ void cstore(float* p, float v) {
    __hip_atomic_store(p, v, __ATOMIC_RELAXED, __HIP_MEMORY_SCOPE_AGENT);
}
__device__ __forceinline__ unsigned long long cload64(const float* p) {
    return __hip_atomic_load((const unsigned long long*)p, __ATOMIC_RELAXED,
                             __HIP_MEMORY_SCOPE_AGENT);
}
__device__ __forceinline__ void cstore64(float* p, unsigned long long v) {
    __hip_atomic_store((unsigned long long*)p, v, __ATOMIC_RELAXED,
                       __HIP_MEMORY_SCOPE_AGENT);
}

__device__ __forceinline__ float wave_reduce_sum(float v) {
#pragma unroll
    for (int m = 32; m >= 1; m >>= 1) v += __shfl_xor(v, m, 64);
    return v;
}

__device__ __forceinline__ float geluf(float y) {
    return 0.5f * y * (1.f + tanhf(0.7978845608028654f * (y + 0.044715f * y * y * y)));
}

// xn[] = rms(coherent-load src)*w, red[] is 256-float scratch. FP order fixed.
__device__ __forceinline__ void load_rms(const float* __restrict__ src,
                                         const float* __restrict__ w,
                                         float* xn, float* red) {
    int tid = threadIdx.x;
    float ss = 0.f;
    for (int i = tid; i < D; i += 256) { float v = cload(src + i); xn[i] = v; ss += v * v; }
    red[tid] = ss;
    __syncthreads();
    for (int s = 128; s > 0; s >>= 1) {
        if (tid < s) red[tid] += red[tid + s];
        __syncthreads();
    }
    float inv = rsqrtf(red[0] / (float)D + 1e-6f);
    for (int i = tid; i < D; i += 256) xn[i] = xn[i] * inv * w[i];
    __syncthreads();
}

// init: h = talker||code0, out tail = code0, zero qkv + barrier counter.
__global__ __launch_bounds__(256) void k_pre(const float* __restrict__ th,
                                             const float* __restrict__ c0,
                                             float* __restrict__ h,
                                             float* __restrict__ out,
                                             float* __restrict__ qkv,
                                             unsigned* __restrict__ cnt) {
    int i = blockIdx.x * 256 + threadIdx.x;   // grid 8 x 256 = 2048
    if (i < 16) cnt[i] = 0u;
    if (i < 1024) {
        h[i] = th[i];
        h[D + i] = c0[i];
        out[NGRP + i] = c0[i];
    }
    for (int j = i; j < 2 * 3 * D; j += 2048) qkv[j] = 0.f;
}

__global__ __launch_bounds__(256, 1) void k_all(Params p) {
    __shared__ float xn[D];
    __shared__ float red[256];
    __shared__ float4 part[4][64];
    __shared__ float s_topv[TOPK];
    __shared__ int   s_topi[TOPK];
    __shared__ int   s_code;

    float* ws   = p.ws;
    float* h    = ws;            // 2*1024
    float* qkvb = ws + 2048;     // 2*3*1024
    float* ao   = ws + 8192;     // 2*1024
    float* kc   = ws + 10240;    // 2*16*1024
    float* vc   = ws + 43008;    // 2*16*1024
    float* ub   = ws + 75776;    // 2*4096
    float* lg   = ws + 83968;    // 2048
    unsigned* cnt = (unsigned*)(ws + 86016);

    const int bid = blockIdx.x;
    const int tid = threadIdx.x;
    unsigned ep = 0;

    float4 rz[16];   // WO weights, prefetched one phase early (static-indexed only)

    // Single-counter barrier: ARRIVE = drain stores + one device-scope RMW;
    // WAITB = thread-0 relaxed poll of the counter, then block barrier.
    // Counter is monotonic (epoch targets), no fences anywhere: all cross-block
    // data moves through coherence-point ops (cload/cstore/atomicAdd).
    auto ARRIVE = [&]() {
        asm volatile("s_waitcnt vmcnt(0) lgkmcnt(0)" ::: "memory");
        __syncthreads();
        if (tid == 0)
            __hip_atomic_fetch_add(cnt, 1u, __ATOMIC_RELAXED, __HIP_MEMORY_SCOPE_AGENT);
    };
    auto WAITB = [&]() {
        ++ep;
        unsigned tgt = ep * NB;
        if (tid == 0) {
            while (__hip_atomic_load(cnt, __ATOMIC_RELAXED, __HIP_MEMORY_SCOPE_AGENT) < tgt)
                __builtin_amdgcn_s_sleep(8);
        }
        __syncthreads();
    };

    auto step = [&](int T, int basePos) {
        for (int l = 0; l < NL; ++l) {
            // ================= QKV: prefetch W -> wait -> rms+fma =================
            {
                bool act = bid < 96 * T;
                float4 r[32];
                int x = bid % 12, y = (bid / 12) % 8, t = bid / 96;
                int m = x >> 2, ob = x & 3;
                int w = tid >> 6, lane = tid & 63;
                int obase = ob * 256, kbase = (y * 4 + w) * 32;
                if (act) {
                    const float* W = ((m == 0) ? p.wq : (m == 1) ? p.wk : p.wv)
                                     + (long)l * D * D;
                    const float* Wp = W + (long)kbase * D + obase + lane * 4;
#pragma unroll
                    for (int i = 0; i < 32; ++i) r[i] = *(const float4*)(Wp + (long)i * D);
                }
                __builtin_amdgcn_sched_barrier(0);
                WAITB();
                if (act) {
                    load_rms(h + t * D, p.ln1 + l * D, xn, red);
                    float4 acc = {0.f, 0.f, 0.f, 0.f};
#pragma unroll
                    for (int i = 0; i < 32; ++i) {
                        float xv = xn[kbase + i];
                        acc.x += xv * r[i].x; acc.y += xv * r[i].y;
                        acc.z += xv * r[i].z; acc.w += xv * r[i].w;
                    }
                    part[w][lane] = acc;
                    __syncthreads();
                    const float* pp2 = (const float*)part;
                    float s = pp2[tid] + pp2[256 + tid] + pp2[512 + tid] + pp2[768 + tid];
                    atomicAdd(&qkvb[t * 3 * D + m * D + obase + tid], s);
                }
                ARRIVE();
            }

            // ====== ATTN (+ prefetch WO weights into rz, + zero ub) ======
            {
                bool wact = bid < 64 * T;
                {
                    int xw = bid % 4, yw = (bid / 4) % 16;
                    int w = tid >> 6, lane = tid & 63;
                    if (wact) {
                        const float* WpO = p.wo + (long)l * D * D
                                         + (long)((yw * 4 + w) * 16) * D + xw * 256 + lane * 4;
#pragma unroll
                        for (int i = 0; i < 16; ++i) rz[i] = *(const float4*)(WpO + (long)i * D);
                    }
                }
                __builtin_amdgcn_sched_barrier(0);
                WAITB();
                for (int i = bid * 256 + tid; i < T * (FF / 2); i += NB * 256)
                    cstore64(&ub[2 * i], 0ull);
                int wid = bid * 4 + (tid >> 6);
                if (wid < T * NHEADS) {
                    int t = wid / NHEADS, hd = wid % NHEADS, d = tid & 63;
                    float* kcl = kc + (long)l * MAXS * D;
                    float* vcl = vc + (long)l * MAXS * D;
                    int pos = basePos + t;
                    int i = d & 31;
                    float inv = __expf(-(float)i * (9.210340371976184f / 32.0f));
                    float ang = (float)pos * inv;
                    float cs = cosf(ang), sn = sinf(ang);

                    float q = cload(&qkvb[t * 3 * D + hd * HDIM + d]);
                    float qp = __shfl_xor(q, 32, 64);
                    float qr = (d < 32) ? (q * cs - qp * sn) : (q * cs + qp * sn);

                    float k0 = cload(&qkvb[t * 3 * D + D + hd * HDIM + d]);
                    float kp = __shfl_xor(k0, 32, 64);
                    float kr = (d < 32) ? (k0 * cs - kp * sn) : (k0 * cs + kp * sn);

                    float v0 = cload(&qkvb[t * 3 * D + 2 * D + hd * HDIM + d]);
                    cstore(&kcl[pos * D + hd * HDIM + d], kr);
                    cstore(&vcl[pos * D + hd * HDIM + d], v0);

                    float sc[MAXS];
#pragma unroll
                    for (int s = 0; s < MAXS; ++s) {
                        if (s > pos) break;
                        float kv;
                        if (s < basePos) {
                            kv = cload(&kcl[s * D + hd * HDIM + d]);
                        } else if (s == pos) {
                            kv = kr;
                        } else {
                            float kk = cload(&qkvb[(s - basePos) * 3 * D + D + hd * HDIM + d]);
                            float kkp = __shfl_xor(kk, 32, 64);
                            float a2 = (float)s * inv;
                            float c2 = cosf(a2), s2 = sinf(a2);
                            kv = (d < 32) ? (kk * c2 - kkp * s2) : (kk * c2 + kkp * s2);
                        }
                        float dt = wave_reduce_sum(qr * kv);
                        sc[s] = dt * 0.125f;
                    }
                    float mx = -1e30f;
#pragma unroll
                    for (int s = 0; s < MAXS; ++s) { if (s > pos) break; mx = fmaxf(mx, sc[s]); }
                    float lsum = 0.f;
#pragma unroll
                    for (int s = 0; s < MAXS; ++s) {
                        if (s > pos) break;
                        sc[s] = expf(sc[s] - mx); lsum += sc[s];
                    }
                    float o = 0.f;
#pragma unroll
                    for (int s = 0; s < MAXS; ++s) {
                        if (s > pos) break;
                        float vv = (s < basePos)
                                 ? cload(&vcl[s * D + hd * HDIM + d])
                                 : cload(&qkvb[(s - basePos) * 3 * D + 2 * D + hd * HDIM + d]);
                        o += sc[s] * vv;
                    }
                    cstore(&ao[t * D + hd * HDIM + d], o / lsum);
                }
                ARRIVE();
            }

            // ============ WO (weights already in rz) + zero qkv ============
            {
                WAITB();
                for (int i = bid * 256 + tid; i < T * 3 * (D / 2); i += NB * 256)
                    cstore64(&qkvb[2 * i], 0ull);
                if (bid < 64 * T) {
                    int x = bid % 4, y = (bid / 4) % 16, t = bid / 64;
                    for (int jj = tid; jj < D / 2; jj += 256) {
                        unsigned long long u = cload64(ao + t * D + 2 * jj);
                        xn[2 * jj]     = __uint_as_float((unsigned)u);
                        xn[2 * jj + 1] = __uint_as_float((unsigned)(u >> 32));
                    }
                    __syncthreads();
                    int w = tid >> 6, lane = tid & 63;
                    int obase = x * 256, kbase = (y * 4 + w) * 16;
                    float4 acc = {0.f, 0.f, 0.f, 0.f};
#pragma unroll
                    for (int i = 0; i < 16; ++i) {
                        float xv = xn[kbase + i];
                        acc.x += xv * rz[i].x; acc.y += xv * rz[i].y;
                        acc.z += xv * rz[i].z; acc.w += xv * rz[i].w;
                    }
                    part[w][lane] = acc;
                    __syncthreads();
                    const float* pp2 = (const float*)part;
                    float s = pp2[tid] + pp2[256 + tid] + pp2[512 + tid] + pp2[768 + tid];
                    atomicAdd(&h[t * D + obase + tid], s);
                }
                ARRIVE();
            }

            // ================= FFN1: prefetch -> wait -> rms+fma =================
            {
                bool act = bid < 128 * T;
                float4 r[32];
                int x = bid % 16, y = (bid / 16) % 8, t = bid / 128;
                int w = tid >> 6, lane = tid & 63;
                int obase = x * 256, kbase = (y * 4 + w) * 32;
                if (act) {
                    const float* Wp = p.w1 + (long)l * D * FF + (long)kbase * FF
                                    + obase + lane * 4;
#pragma unroll
                    for (int i = 0; i < 32; ++i) r[i] = *(const float4*)(Wp + (long)i * FF);
                }
                __builtin_amdgcn_sched_barrier(0);
                WAITB();
                if (act) {
                    load_rms(h + t * D, p.ln2 + l * D, xn, red);
                    float4 acc = {0.f, 0.f, 0.f, 0.f};
#pragma unroll
                    for (int i = 0; i < 32; ++i) {
                        float xv = xn[kbase + i];
                        acc.x += xv * r[i].x; acc.y += xv * r[i].y;
                        acc.z += xv * r[i].z; acc.w += xv * r[i].w;
                    }
                    part[w][lane] = acc;
                    __syncthreads();
                    const float* pp2 = (const float*)part;
                    float s = pp2[tid] + pp2[256 + tid] + pp2[512 + tid] + pp2[768 + tid];
                    atomicAdd(&ub[t * FF + obase + tid], s);
                }
                ARRIVE();
            }

            // ================= FFN2: prefetch -> wait -> gelu+fma =================
            {
                bool act = bid < 128 * T;
                float4 r[32];
                int x = bid % 4, y = (bid / 4) % 32, t = bid / 128;
                int kblk = y * 128;
                int w = tid >> 6, lane = tid & 63;
                int obase = x * 256, kloc = w * 32;
                if (act) {
                    const float* Wp = p.w2 + (long)l * FF * D + (long)(kblk + kloc) * D
                                    + obase + lane * 4;
#pragma unroll
                    for (int i = 0; i < 32; ++i) r[i] = *(const float4*)(Wp + (long)i * D);
                }
                __builtin_amdgcn_sched_barrier(0);
                WAITB();
                if (act) {
                    if (tid < 64) {
                        unsigned long long u = cload64(&ub[t * FF + kblk + 2 * tid]);
                        red[2 * tid]     = geluf(__uint_as_float((unsigned)u));
                        red[2 * tid + 1] = geluf(__uint_as_float((unsigned)(u >> 32)));
                    }
                    __syncthreads();
                    float4 acc = {0.f, 0.f, 0.f, 0.f};
#pragma unroll
                    for (int i = 0; i < 32; ++i) {
                        float xv = red[kloc + i];
                        acc.x += xv * r[i].x; acc.y += xv * r[i].y;
                        acc.z += xv * r[i].z; acc.w += xv * r[i].w;
                    }
                    part[w][lane] = acc;
                    __syncthreads();
                    const float* pp2 = (const float*)part;
                    float s = pp2[tid] + pp2[256 + tid] + pp2[512 + tid] + pp2[768 + tid];
                    atomicAdd(&h[t * D + obase + tid], s);
                }
                ARRIVE();
            }
        }
    };

    ARRIVE();          // startup barrier arm (matches first phase's WAITB)
    step(2, 0);        // prefill (2 tokens)

    for (int g = 0; g < NGRP; ++g) {
        // ================= HEAD: prefetch rows -> wait -> rms+dots =================
        {
            bool act = bid < 128;
            float4 r[16];
            int lane = tid & 63, w = tid >> 6;
            int rbase = bid * 16 + w * 4;
            if (act) {
                const float* Hd = p.heads + (long)g * VOC * D;
#pragma unroll
                for (int rr = 0; rr < 4; ++rr) {
                    const float* row = Hd + (long)(rbase + rr) * D;
#pragma unroll
                    for (int it = 0; it < 4; ++it)
                        r[rr * 4 + it] = *(const float4*)(row + it * 256 + lane * 4);
                }
            }
            __builtin_amdgcn_sched_barrier(0);
            WAITB();
            if (act) {
                const float* hid = h + ((g == 0) ? D : 0);
                load_rms(hid, p.lnf, xn, red);
#pragma unroll
                for (int rr = 0; rr < 4; ++rr) {
                    float acc = 0.f;
#pragma unroll
                    for (int it = 0; it < 4; ++it) {
                        int idx = it * 256 + lane * 4;
                        float4 a = r[rr * 4 + it];
                        acc += a.x * xn[idx] + a.y * xn[idx + 1]
                             + a.z * xn[idx + 2] + a.w * xn[idx + 3];
                    }
                    acc = wave_reduce_sum(acc);
                    if (lane == 0) cstore(&lg[rbase + rr], acc);
                }
            }
            ARRIVE();
        }

        // ================= SAMPLE: block 0 only =================
        {
            WAITB();
            if (bid == 0) {
                if (tid < 64) {
                    int lane = tid;
                    float v[32];
#pragma unroll
                    for (int j = 0; j < 32; ++j) v[j] = cload(&lg[j * 64 + lane]);
                    for (int r = 0; r < TOPK; ++r) {
                        float bv = v[0];
                        int bj = 0;
#pragma unroll
                        for (int j = 1; j < 32; ++j)
                            if (v[j] > bv) { bv = v[j]; bj = j; }
                        int bidx = bj * 64 + lane;
#pragma unroll
                        for (int m = 32; m >= 1; m >>= 1) {
                            float ov = __shfl_xor(bv, m, 64);
                            int oi = __shfl_xor(bidx, m, 64);
                            if (ov > bv || (ov == bv && oi < bidx)) { bv = ov; bidx = oi; }
                        }
                        if (lane == 0) { s_topv[r] = bv; s_topi[r] = bidx; }
                        if ((bidx & 63) == lane) v[bidx >> 6] = -3.0e38f;
                    }
                }
                __syncthreads();
                if (tid == 0) {
                    float t = fmaxf(p.temp[0], 1e-5f);
                    float m = s_topv[0] / t;
                    float pr[TOPK];
                    float l = 0.f;
                    for (int j = 0; j < TOPK; ++j) { pr[j] = expf(s_topv[j] / t - m); l += pr[j]; }
                    float u = p.unis[g];
                    u = fminf(fmaxf(u, 1e-6f), 1.f - 1e-6f);
                    float cdf = 0.f;
                    int choice = 0;
                    bool found = false;
                    for (int j = 0; j < TOPK; ++j) {
                        cdf += pr[j] / l;
                        if (!found && cdf >= u) { choice = j; found = true; }
                    }
                    s_code = s_topi[choice];
                    p.out[g] = (float)s_code;
                }
                __syncthreads();
                int code = s_code;
                const float* e = p.embeds + ((long)g * VOC + code) * D;
                for (int i = tid; i < D; i += 256) {
                    float ev = e[i];
                    p.out[NGRP + i] += ev;
                    cstore(&h[i], ev);
                }
            }
            ARRIVE();
        }

        if (g + 1 < NGRP) step(1, g + 2);
    }
}

extern "C" void kernel_launch(void* const* d_in, const int* in_sizes, int n_in,
                              void* d_out, int out_size, void* d_ws, size_t ws_size,
                              hipStream_t stream) {
    const float* talker = (const float*)d_in[0];
    const float* code0  = (const float*)d_in[1];
    const float* temp   = (const float*)d_in[2];
    const float* unis   = (const float*)d_in[3];
    const float* heads  = (const float*)d_in[4];
    const float* embeds = (const float*)d_in[5];
    const float* ln1    = (const float*)d_in[6];
    const float* ln2    = (const float*)d_in[7];
    const float* lnf    = (const float*)d_in[8];
    const float* wq     = (const float*)d_in[9];
    const float* wk     = (const float*)d_in[10];
    const float* wv     = (const float*)d_in[11];
    const float* wo     = (const float*)d_in[12];
    const float* w1     = (const float*)d_in[13];
    const float* w2     = (const float*)d_in[14];
    float* out = (float*)d_out;

    float* ws   = (float*)d_ws;
    float* h    = ws;
    float* qkvb = ws + 2048;
    unsigned* cnt = (unsigned*)(ws + 86016);

    k_pre<<<8, 256, 0, stream>>>(talker, code0, h, out, qkvb, cnt);

    Params pr{talker, code0, temp, unis, heads, embeds, ln1, ln2, lnf,
              wq, wk, wv, wo, w1, w2, out, ws};
    // 256 blocks x 256 threads, 1 block/CU on 256 CUs: all blocks co-resident,
    // so the device-side monotonic-counter barrier cannot deadlock.
    k_all<<<dim3(NB), dim3(256), 0, stream>>>(pr);
}

// Round 4
// 2623.852 us; speedup vs baseline: 1.2113x; 1.2113x over previous
//
#include <hip/hip_runtime.h>
#include <math.h>

#define D      1024
#define NHEADS 16
#define HDIM   64
#define NL     2
#define FF     4096
#define NGRP   15
#define VOC    2048
#define TOPK   50
#define MAXS   16
#define NB     128
#define NC     10   // phase counters: QKV0,AWO0,FF1_0,FF2_0,QKV1,AWO1,FF1_1,FF2_1,HEAD,SAMPLE

struct Params {
    const float* talker; const float* code0; const float* temp; const float* unis;
    const float* heads;  const float* embeds;
    const float* ln1; const float* ln2; const float* lnf;
    const float* wq; const float* wk; const float* wv; const float* wo;
    const float* w1; const float* w2;
    float* out; float* ws;
};

// Coherence-point access for cross-block mutable buffers (bypasses non-coherent
// per-XCD caches; no cache-maintenance fences needed; MLP preserved).
__device__ __forceinline__ float cload(const float* p) {
    return __hip_atomic_load(p, __ATOMIC_RELAXED, __HIP_MEMORY_SCOPE_AGENT);
}
__device__ __forceinline__ void cstore(float* p, float v) {
    __hip_atomic_store(p, v, __ATOMIC_RELAXED, __HIP_MEMORY_SCOPE_AGENT);
}
__device__ __forceinline__ unsigned long long cload64(const float* p) {
    return __hip_atomic_load((const unsigned long long*)p, __ATOMIC_RELAXED,
                             __HIP_MEMORY_SCOPE_AGENT);
}
__device__ __forceinline__ void cstore64(float* p, unsigned long long v) {
    __hip_atomic_store((unsigned long long*)p, v, __ATOMIC_RELAXED,
                       __HIP_MEMORY_SCOPE_AGENT);
}

__device__ __forceinline__ float wave_reduce_sum(float v) {
#pragma unroll
    for (int m = 32; m >= 1; m >>= 1) v += __shfl_xor(v, m, 64);
    return v;
}

__device__ __forceinline__ float geluf(float y) {
    return 0.5f * y * (1.f + tanhf(0.7978845608028654f * (y + 0.044715f * y * y * y)));
}

// xn[] = rms(coherent-load src)*w, red[] is 256-float scratch. FP order fixed.
__device__ __forceinline__ void load_rms(const float* __restrict__ src,
                                         const float* __restrict__ w,
                                         float* xn, float* red) {
    int tid = threadIdx.x;
    float ss = 0.f;
    for (int i = tid; i < D; i += 256) { float v = cload(src + i); xn[i] = v; ss += v * v; }
    red[tid] = ss;
    __syncthreads();
    for (int s = 128; s > 0; s >>= 1) {
        if (tid < s) red[tid] += red[tid + s];
        __syncthreads();
    }
    float inv = rsqrtf(red[0] / (float)D + 1e-6f);
    for (int i = tid; i < D; i += 256) xn[i] = xn[i] * inv * w[i];
    __syncthreads();
}

// init: h = talker||code0, out tail = code0, zero qkv + phase counters.
__global__ __launch_bounds__(256) void k_pre(const float* __restrict__ th,
                                             const float* __restrict__ c0,
                                             float* __restrict__ h,
                                             float* __restrict__ out,
                                             float* __restrict__ qkv,
                                             unsigned* __restrict__ ctr) {
    int i = blockIdx.x * 256 + threadIdx.x;   // grid 8 x 256 = 2048
    if (i < NC * 16) ctr[i] = 0u;
    if (i < 1024) {
        h[i] = th[i];
        h[D + i] = c0[i];
        out[NGRP + i] = c0[i];
    }
    for (int j = i; j < 2 * 3 * D; j += 2048) qkv[j] = 0.f;
}

__global__ __launch_bounds__(256) void k_all(Params p) {
    __shared__ float xn[D];
    __shared__ float red[256];
    __shared__ float4 part[4][64];
    __shared__ float s_topv[TOPK];
    __shared__ int   s_topi[TOPK];
    __shared__ int   s_code;

    float* ws   = p.ws;
    float* h    = ws;            // 2*1024
    float* qkvb = ws + 2048;     // 2*3*1024
    float* kc   = ws + 10240;    // 2*16*1024
    float* vc   = ws + 43008;    // 2*16*1024
    float* ub   = ws + 75776;    // 2*4096
    float* lg   = ws + 83968;    // 2048
    unsigned* ctr = (unsigned*)(ws + 86016);  // NC counters, 64B apart

    const int bid = blockIdx.x;
    const int tid = threadIdx.x;

    // Per-block cumulative targets; every block updates identically every phase.
    unsigned tgt[NC];
#pragma unroll
    for (int k = 0; k < NC; ++k) tgt[k] = 0u;

    // Consumer wait: poll this phase's counter until all producers arrived.
    auto waitc = [&](int k) {
        if (tid == 0) {
            while (__hip_atomic_load(&ctr[k * 16], __ATOMIC_RELAXED,
                                     __HIP_MEMORY_SCOPE_AGENT) < tgt[k])
                __builtin_amdgcn_s_sleep(1);
        }
        __syncthreads();
    };
    // Producer arrive: each wave drains its VMEM (data at IF), block barrier,
    // then one device-scope RMW.
    auto arrive = [&](int k) {
        asm volatile("s_waitcnt vmcnt(0) lgkmcnt(0)" ::: "memory");
        __syncthreads();
        if (tid == 0)
            __hip_atomic_fetch_add(&ctr[k * 16], 1u, __ATOMIC_RELAXED,
                                   __HIP_MEMORY_SCOPE_AGENT);
    };

    auto step = [&](int T, int basePos) {
        for (int l = 0; l < NL; ++l) {
            // ======== QKV: tasks 12x8xT; waits SAMPLE (l=0) / FF2[l-1] ========
            {
                int Pq = (96 * T > NB) ? NB : 96 * T;
                int widx = (l == 0) ? 9 : 4 * (l - 1) + 3;
                if (bid < Pq) {
                    waitc(widx);
                    for (int task = bid; task < 96 * T; task += NB) {
                        int x = task % 12, y = (task / 12) % 8, t = task / 96;
                        int m = x >> 2, ob = x & 3;
                        load_rms(h + t * D, p.ln1 + l * D, xn, red);
                        int w = tid >> 6, lane = tid & 63;
                        int obase = ob * 256, kbase = (y * 4 + w) * 32;
                        const float* W = ((m == 0) ? p.wq : (m == 1) ? p.wk : p.wv)
                                         + (long)l * D * D;
                        const float* Wp = W + (long)kbase * D + obase + lane * 4;
                        float4 acc = {0.f, 0.f, 0.f, 0.f};
#pragma unroll 4
                        for (int i = 0; i < 32; ++i) {
                            float xv = xn[kbase + i];
                            float4 wv4 = *(const float4*)(Wp + (long)i * D);
                            acc.x += xv * wv4.x; acc.y += xv * wv4.y;
                            acc.z += xv * wv4.z; acc.w += xv * wv4.w;
                        }
                        part[w][lane] = acc;
                        __syncthreads();
                        const float* pp2 = (const float*)part;
                        float s = pp2[tid] + pp2[256 + tid] + pp2[512 + tid] + pp2[768 + tid];
                        atomicAdd(&qkvb[t * 3 * D + m * D + obase + tid], s);
                    }
                    arrive(4 * l + 0);
                }
                tgt[4 * l + 0] += Pq;
            }

            // ======== AWO (fused attn + WO): blocks (t,hd,chunk) = 64T ========
            {
                int Pa = 64 * T;
                if (bid < Pa) {
                    waitc(4 * l + 0);
                    // zero ub (consumed by prev FF2, guaranteed via transitive chain)
                    for (int i = bid * 256 + tid; i < T * (FF / 2); i += Pa * 256)
                        cstore64(&ub[2 * i], 0ull);
                    int chunk = bid & 3, hd = (bid >> 2) & 15, t = bid >> 6;
                    int w = tid >> 6, lane = tid & 63;
                    if (w == 0) {   // wave 0: softmax for this head (redundant x4, cheap)
                        int d = lane;
                        float* kcl = kc + (long)l * MAXS * D;
                        float* vcl = vc + (long)l * MAXS * D;
                        int pos = basePos + t;
                        int i = d & 31;
                        float inv = __expf(-(float)i * (9.210340371976184f / 32.0f));
                        float ang = (float)pos * inv;
                        float cs = cosf(ang), sn = sinf(ang);

                        float q = cload(&qkvb[t * 3 * D + hd * HDIM + d]);
                        float qp = __shfl_xor(q, 32, 64);
                        float qr = (d < 32) ? (q * cs - qp * sn) : (q * cs + qp * sn);

                        float k0 = cload(&qkvb[t * 3 * D + D + hd * HDIM + d]);
                        float kp = __shfl_xor(k0, 32, 64);
                        float kr = (d < 32) ? (k0 * cs - kp * sn) : (k0 * cs + kp * sn);

                        float v0 = cload(&qkvb[t * 3 * D + 2 * D + hd * HDIM + d]);
                        cstore(&kcl[pos * D + hd * HDIM + d], kr);   // idempotent x4
                        cstore(&vcl[pos * D + hd * HDIM + d], v0);

                        float sc[MAXS];
#pragma unroll
                        for (int s = 0; s < MAXS; ++s) {
                            if (s > pos) break;
                            float kv;
                            if (s < basePos) {
                                kv = cload(&kcl[s * D + hd * HDIM + d]);
                            } else if (s == pos) {
                                kv = kr;
                            } else {
                                float kk = cload(&qkvb[(s - basePos) * 3 * D + D + hd * HDIM + d]);
                                float kkp = __shfl_xor(kk, 32, 64);
                                float a2 = (float)s * inv;
                                float c2 = cosf(a2), s2 = sinf(a2);
                                kv = (d < 32) ? (kk * c2 - kkp * s2) : (kk * c2 + kkp * s2);
                            }
                            float dt = wave_reduce_sum(qr * kv);
                            sc[s] = dt * 0.125f;
                        }
                        float mx = -1e30f;
#pragma unroll
                        for (int s = 0; s < MAXS; ++s) { if (s > pos) break; mx = fmaxf(mx, sc[s]); }
                        float lsum = 0.f;
#pragma unroll
                        for (int s = 0; s < MAXS; ++s) {
                            if (s > pos) break;
                            sc[s] = expf(sc[s] - mx); lsum += sc[s];
                        }
                        float o = 0.f;
#pragma unroll
                        for (int s = 0; s < MAXS; ++s) {
                            if (s > pos) break;
                            float vv = (s < basePos)
                                     ? cload(&vcl[s * D + hd * HDIM + d])
                                     : cload(&qkvb[(s - basePos) * 3 * D + 2 * D + hd * HDIM + d]);
                            o += sc[s] * vv;
                        }
                        red[d] = o / lsum;   // broadcast head-output to block
                    }
                    __syncthreads();
                    // partial WO: rows [hd*64 + w*16, +16), cols [chunk*256, +256)
                    int obase = chunk * 256, kbase = hd * HDIM + w * 16;
                    const float* Wp = p.wo + (long)l * D * D + (long)kbase * D
                                    + obase + lane * 4;
                    float4 acc = {0.f, 0.f, 0.f, 0.f};
#pragma unroll
                    for (int i = 0; i < 16; ++i) {
                        float xv = red[w * 16 + i];
                        float4 wv4 = *(const float4*)(Wp + (long)i * D);
                        acc.x += xv * wv4.x; acc.y += xv * wv4.y;
                        acc.z += xv * wv4.z; acc.w += xv * wv4.w;
                    }
                    part[w][lane] = acc;
                    __syncthreads();
                    const float* pp2 = (const float*)part;
                    float s = pp2[tid] + pp2[256 + tid] + pp2[512 + tid] + pp2[768 + tid];
                    atomicAdd(&h[t * D + obase + tid], s);
                    arrive(4 * l + 1);
                }
                tgt[4 * l + 1] += Pa;
            }

            // ======== FFN1: all NB blocks; also zeroes qkvb for next QKV ========
            {
                waitc(4 * l + 1);
                for (int i = bid * 256 + tid; i < T * 3 * (D / 2); i += NB * 256)
                    cstore64(&qkvb[2 * i], 0ull);
                for (int task = bid; task < 128 * T; task += NB) {
                    int x = task % 16, y = (task / 16) % 8, t = task / 128;
                    load_rms(h + t * D, p.ln2 + l * D, xn, red);
                    int w = tid >> 6, lane = tid & 63;
                    int obase = x * 256, kbase = (y * 4 + w) * 32;
                    const float* Wp = p.w1 + (long)l * D * FF + (long)kbase * FF
                                    + obase + lane * 4;
                    float4 acc = {0.f, 0.f, 0.f, 0.f};
#pragma unroll 4
                    for (int i = 0; i < 32; ++i) {
                        float xv = xn[kbase + i];
                        float4 wv4 = *(const float4*)(Wp + (long)i * FF);
                        acc.x += xv * wv4.x; acc.y += xv * wv4.y;
                        acc.z += xv * wv4.z; acc.w += xv * wv4.w;
                    }
                    part[w][lane] = acc;
                    __syncthreads();
                    const float* pp2 = (const float*)part;
                    float s = pp2[tid] + pp2[256 + tid] + pp2[512 + tid] + pp2[768 + tid];
                    atomicAdd(&ub[t * FF + obase + tid], s);
                }
                arrive(4 * l + 2);
                tgt[4 * l + 2] += NB;
            }

            // ======== FFN2: all NB blocks ========
            {
                waitc(4 * l + 2);
                for (int task = bid; task < 128 * T; task += NB) {
                    int x = task % 4, y = (task / 4) % 32, t = task / 128;
                    int kblk = y * 128;
                    if (tid < 64) {
                        unsigned long long u = cload64(&ub[t * FF + kblk + 2 * tid]);
                        red[2 * tid]     = geluf(__uint_as_float((unsigned)u));
                        red[2 * tid + 1] = geluf(__uint_as_float((unsigned)(u >> 32)));
                    }
                    __syncthreads();
                    int w = tid >> 6, lane = tid & 63;
                    int obase = x * 256, kloc = w * 32;
                    const float* Wp = p.w2 + (long)l * FF * D + (long)(kblk + kloc) * D
                                    + obase + lane * 4;
                    float4 acc = {0.f, 0.f, 0.f, 0.f};
#pragma unroll 4
                    for (int i = 0; i < 32; ++i) {
                        float xv = red[kloc + i];
                        float4 wv4 = *(const float4*)(Wp + (long)i * D);
                        acc.x += xv * wv4.x; acc.y += xv * wv4.y;
                        acc.z += xv * wv4.z; acc.w += xv * wv4.w;
                    }
                    part[w][lane] = acc;
                    __syncthreads();
                    const float* pp2 = (const float*)part;
                    float s = pp2[tid] + pp2[256 + tid] + pp2[512 + tid] + pp2[768 + tid];
                    atomicAdd(&h[t * D + obase + tid], s);
                }
                arrive(4 * l + 3);
                tgt[4 * l + 3] += NB;
            }
        }
    };

    step(2, 0);   // prefill

    for (int g = 0; g < NGRP; ++g) {
        // ======== HEAD: all NB blocks, 16 rows each; waits FF2[l=1] ========
        {
            waitc(7);
            const float* hid = h + ((g == 0) ? D : 0);
            load_rms(hid, p.lnf, xn, red);
            int lane = tid & 63, w = tid >> 6;
            int rbase = bid * 16 + w * 4;
            const float* Hd = p.heads + (long)g * VOC * D;
#pragma unroll
            for (int rr = 0; rr < 4; ++rr) {
                const float* row = Hd + (long)(rbase + rr) * D;
                float acc = 0.f;
#pragma unroll
                for (int it = 0; it < 4; ++it) {
                    int idx = it * 256 + lane * 4;
                    float4 a = *(const float4*)(row + idx);
                    acc += a.x * xn[idx] + a.y * xn[idx + 1]
                         + a.z * xn[idx + 2] + a.w * xn[idx + 3];
                }
                acc = wave_reduce_sum(acc);
                if (lane == 0) cstore(&lg[rbase + rr], acc);
            }
            arrive(8);
            tgt[8] += NB;
        }

        // ======== SAMPLE: block 0 only; waits HEAD ========
        {
            if (bid == 0) {
                waitc(8);
                if (tid < 64) {
                    int lane = tid;
                    float v[32];
#pragma unroll
                    for (int j = 0; j < 32; ++j) v[j] = cload(&lg[j * 64 + lane]);
                    for (int r = 0; r < TOPK; ++r) {
                        float bv = v[0];
                        int bj = 0;
#pragma unroll
                        for (int j = 1; j < 32; ++j)
                            if (v[j] > bv) { bv = v[j]; bj = j; }
                        int bidx = bj * 64 + lane;
#pragma unroll
                        for (int m = 32; m >= 1; m >>= 1) {
                            float ov = __shfl_xor(bv, m, 64);
                            int oi = __shfl_xor(bidx, m, 64);
                            if (ov > bv || (ov == bv && oi < bidx)) { bv = ov; bidx = oi; }
                        }
                        if (lane == 0) { s_topv[r] = bv; s_topi[r] = bidx; }
                        if ((bidx & 63) == lane) v[bidx >> 6] = -3.0e38f;
                    }
                }
                __syncthreads();
                if (tid == 0) {
                    float t = fmaxf(p.temp[0], 1e-5f);
                    float m = s_topv[0] / t;
                    float pr[TOPK];
                    float l = 0.f;
                    for (int j = 0; j < TOPK; ++j) { pr[j] = expf(s_topv[j] / t - m); l += pr[j]; }
                    float u = p.unis[g];
                    u = fminf(fmaxf(u, 1e-6f), 1.f - 1e-6f);
                    float cdf = 0.f;
                    int choice = 0;
                    bool found = false;
                    for (int j = 0; j < TOPK; ++j) {
                        cdf += pr[j] / l;
                        if (!found && cdf >= u) { choice = j; found = true; }
                    }
                    s_code = s_topi[choice];
                    p.out[g] = (float)s_code;
                }
                __syncthreads();
                int code = s_code;
                const float* e = p.embeds + ((long)g * VOC + code) * D;
                for (int i = tid; i < D; i += 256) {
                    float ev = e[i];
                    p.out[NGRP + i] += ev;
                    cstore(&h[i], ev);
                }
                arrive(9);
            }
            tgt[9] += 1;
        }

        if (g + 1 < NGRP) step(1, g + 2);
    }
}

extern "C" void kernel_launch(void* const* d_in, const int* in_sizes, int n_in,
                              void* d_out, int out_size, void* d_ws, size_t ws_size,
                              hipStream_t stream) {
    const float* talker = (const float*)d_in[0];
    const float* code0  = (const float*)d_in[1];
    const float* temp   = (const float*)d_in[2];
    const float* unis   = (const float*)d_in[3];
    const float* heads  = (const float*)d_in[4];
    const float* embeds = (const float*)d_in[5];
    const float* ln1    = (const float*)d_in[6];
    const float* ln2    = (const float*)d_in[7];
    const float* lnf    = (const float*)d_in[8];
    const float* wq     = (const float*)d_in[9];
    const float* wk     = (const float*)d_in[10];
    const float* wv     = (const float*)d_in[11];
    const float* wo     = (const float*)d_in[12];
    const float* w1     = (const float*)d_in[13];
    const float* w2     = (const float*)d_in[14];
    float* out = (float*)d_out;

    float* ws   = (float*)d_ws;
    float* h    = ws;
    float* qkvb = ws + 2048;
    unsigned* ctr = (unsigned*)(ws + 86016);

    k_pre<<<8, 256, 0, stream>>>(talker, code0, h, out, qkvb, ctr);

    Params pr{talker, code0, temp, unis, heads, embeds, ln1, ln2, lnf,
              wq, wk, wv, wo, w1, w2, out, ws};
    // 128 blocks x 256 threads: all co-resident (<= 256 CUs); producer-consumer
    // counter waits are satisfied in dependency order -> no deadlock.
    k_all<<<dim3(NB), dim3(256), 0, stream>>>(pr);
}